// Round 1
// baseline (144.906 us; speedup 1.0000x reference)
//
#include <hip/hip_runtime.h>
#include <hip/hip_bf16.h>

#define BATCH 1024
#define NL    64
#define DIN   512
#define DOUT  512

#define BM 128
#define BN 128
#define BK 32
#define LDSS 40   // padded LDS row stride in bf16 elems (80 B -> bank-stride 20, 2-way max)

typedef short short8 __attribute__((ext_vector_type(8)));
typedef float f32x4  __attribute__((ext_vector_type(4)));

__device__ __forceinline__ unsigned int f2bf(float f) {
    unsigned int u = __builtin_bit_cast(unsigned int, f);
    u += 0x7fffu + ((u >> 16) & 1u);   // RNE
    return u >> 16;
}

__global__ __launch_bounds__(256) void nlinear_kernel(
        const float* __restrict__ x, const float* __restrict__ w,
        const float* __restrict__ bias, float* __restrict__ out) {
    __shared__ unsigned short As[BM * LDSS];
    __shared__ unsigned short Bs[BN * LDSS];

    const int tid   = threadIdx.x;
    const int bx    = blockIdx.x;
    const int layer = bx >> 5;          // 32 tiles per layer (8 m-tiles x 4 n-tiles)
    const int tile  = bx & 31;
    const int bm0   = (tile >> 2) * BM;
    const int bn0   = (tile & 3) * BN;

    const int wid  = tid >> 6;
    const int lane = tid & 63;
    const int wr   = wid >> 1;          // 2x2 wave grid, each wave 64x64
    const int wc   = wid & 1;
    const int lrow = lane & 15;         // frag row/col selector
    const int lkb  = lane >> 4;         // k-block 0..3

    f32x4 acc[4][4];
#pragma unroll
    for (int i = 0; i < 4; ++i)
#pragma unroll
        for (int j = 0; j < 4; ++j) acc[i][j] = (f32x4){0.f, 0.f, 0.f, 0.f};

    // staging geometry
    // A: 128 rows x 32 k  = 1024 float4 loads -> 4 per thread
    // B: 32 k  x 128 cols -> each thread owns a 4x4 block: kq = tid>>5 (k*4), c4 = (tid&31)*4
    const int kq = tid >> 5;
    const int c4 = (tid & 31) << 2;

    const float* xb = x + (size_t)bm0 * (NL * DIN) + (size_t)layer * DIN;
    const float* wb = w + (size_t)layer * DIN * DOUT + bn0;

    for (int ks = 0; ks < DIN / BK; ++ks) {
        const int k0 = ks * BK;

        // ---- stage A (fp32 -> bf16) ----
#pragma unroll
        for (int it = 0; it < 4; ++it) {
            int flat = it * 256 + tid;
            int row  = flat >> 3;
            int kc   = flat & 7;
            float4 v = *reinterpret_cast<const float4*>(
                xb + (size_t)row * (NL * DIN) + k0 + kc * 4);
            unsigned int lo = f2bf(v.x) | (f2bf(v.y) << 16);
            unsigned int hi = f2bf(v.z) | (f2bf(v.w) << 16);
            *reinterpret_cast<uint2*>(&As[row * LDSS + kc * 4]) = make_uint2(lo, hi);
        }

        // ---- stage B with 4x4 register transpose: LDS layout [n][k] ----
        float4 bv[4];
#pragma unroll
        for (int i = 0; i < 4; ++i)
            bv[i] = *reinterpret_cast<const float4*>(
                wb + (size_t)(k0 + kq * 4 + i) * DOUT + c4);
#pragma unroll
        for (int j = 0; j < 4; ++j) {
            const float* e0 = reinterpret_cast<const float*>(&bv[0]);
            const float* e1 = reinterpret_cast<const float*>(&bv[1]);
            const float* e2 = reinterpret_cast<const float*>(&bv[2]);
            const float* e3 = reinterpret_cast<const float*>(&bv[3]);
            unsigned int lo = f2bf(e0[j]) | (f2bf(e1[j]) << 16);
            unsigned int hi = f2bf(e2[j]) | (f2bf(e3[j]) << 16);
            *reinterpret_cast<uint2*>(&Bs[(c4 + j) * LDSS + kq * 4]) = make_uint2(lo, hi);
        }

        __syncthreads();

        // ---- compute ----
        short8 af[4], bf[4];
#pragma unroll
        for (int mi = 0; mi < 4; ++mi)
            af[mi] = *reinterpret_cast<const short8*>(
                &As[(wr * 64 + mi * 16 + lrow) * LDSS + lkb * 8]);
#pragma unroll
        for (int ni = 0; ni < 4; ++ni)
            bf[ni] = *reinterpret_cast<const short8*>(
                &Bs[(wc * 64 + ni * 16 + lrow) * LDSS + lkb * 8]);
#pragma unroll
        for (int mi = 0; mi < 4; ++mi)
#pragma unroll
            for (int ni = 0; ni < 4; ++ni)
                acc[mi][ni] = __builtin_amdgcn_mfma_f32_16x16x32_bf16(
                    af[mi], bf[ni], acc[mi][ni], 0, 0, 0);

        __syncthreads();
    }

    // ---- epilogue: + bias, fp32 store ----
    const float* bb = bias + (size_t)layer * DOUT + bn0;
    float* ob = out + (size_t)bm0 * (NL * DOUT) + (size_t)layer * DOUT + bn0;
#pragma unroll
    for (int mi = 0; mi < 4; ++mi) {
#pragma unroll
        for (int ni = 0; ni < 4; ++ni) {
            int col = wc * 64 + ni * 16 + lrow;
            float bval = bb[col];
#pragma unroll
            for (int r = 0; r < 4; ++r) {
                int row = wr * 64 + mi * 16 + lkb * 4 + r;
                ob[(size_t)row * (NL * DOUT) + col] = acc[mi][ni][r] + bval;
            }
        }
    }
}

extern "C" void kernel_launch(void* const* d_in, const int* in_sizes, int n_in,
                              void* d_out, int out_size, void* d_ws, size_t ws_size,
                              hipStream_t stream) {
    const float* x  = (const float*)d_in[0];
    const float* w  = (const float*)d_in[1];
    const float* b  = (const float*)d_in[2];
    float* out      = (float*)d_out;

    dim3 grid(NL * (BATCH / BM) * (DOUT / BN));   // 64 * 8 * 4 = 2048
    dim3 block(256);
    hipLaunchKernelGGL(nlinear_kernel, grid, block, 0, stream, x, w, b, out);
}